// Round 5
// baseline (440.231 us; speedup 1.0000x reference)
//
#include <hip/hip_runtime.h>
#include <hip/hip_bf16.h>

// Decoder: one-hot@Wx gather -> 64-step LSTM -> Bahdanau attention softmax.
// B=32, T=64, S=64, U=512, 4U=2048, VOCAB=65.
//
// Round 5: self-announcing data exchange. r4 = 4.93us/step from a 4-round-
// trip sync chain (store-ack, flag store, poll detect, data reload). Now h
// is stored as dwordx2 {bf16-pair, epoch} (one 8B transaction -> tag implies
// data); consumers poll the tagged data directly -- the successful poll IS
// the reload. Ack wait, flag store, flag poll, and separate reload deleted.
// Each wave polls its kt-half (64 transient VGPRs), halves swapped between
// partner waves via LDS. Tags are monotonic per location => correct across
// graph replays without any memset; flags/memset dispatch removed.

#define NB 32
#define NT 64
#define NS 64
#define NU 512
#define N4U 2048
#define NV 65
#define NWG 32

typedef unsigned int u32;
typedef __bf16 bf16_t;
typedef bf16_t bf16x8 __attribute__((ext_vector_type(8)));
typedef float f32x4 __attribute__((ext_vector_type(4)));
typedef u32 u32x4 __attribute__((ext_vector_type(4)));
typedef u32 u32x2 __attribute__((ext_vector_type(2)));

__device__ __forceinline__ unsigned short f2bf(float f) {
  u32 u = __builtin_bit_cast(u32, f);
  u += 0x7fffu + ((u >> 16) & 1u);   // round-to-nearest-even
  return (unsigned short)(u >> 16);
}
__device__ __forceinline__ float bf2f(unsigned short s) {
  return __builtin_bit_cast(float, (u32)s << 16);
}
__device__ __forceinline__ u32 pk2(float a, float b) {
  return (u32)f2bf(a) | ((u32)f2bf(b) << 16);
}
__device__ __forceinline__ float sigf(float x) { return 1.0f / (1.0f + __expf(-x)); }
__device__ __forceinline__ float tanhfast(float x) {
  float e = __expf(2.0f * x);
  return 1.0f - 2.0f / (e + 1.0f);
}

// ---------------------------------------------------------------------------
// LSTM: 32 wgs x 256 threads. Wave (wm,wn): wm = batch-half (rows wm*16..),
// wn = z-col-half AND kt-poll-half. wg g owns h units [g*16, g*16+16).
// Exchange buffer hbuf2: [parity 2][row 32][pair 256][{data,tag} 2] u32.
// ---------------------------------------------------------------------------
__global__ __launch_bounds__(256, 1)
void lstm_kernel(const int* __restrict__ labels,
                 const float* __restrict__ h0,
                 const float* __restrict__ c0,
                 const float* __restrict__ Wx,
                 const float* __restrict__ Wh,
                 const float* __restrict__ bias,
                 u32* __restrict__ hbuf2,   // [2][32][256][2] tagged bf16-pairs
                 u32* __restrict__ dec_u)   // [32*64][256] bf16-pairs
{
  __shared__ float z_buf[NB][65];            // padded: conflict-free gate reads
  __shared__ float c_lds[NB][16];
  __shared__ float wx_lds[NV][65];           // Wx slice + bias folded, padded
  __shared__ unsigned char lab_lds[NB * NT];
  __shared__ __align__(16) u32 hx[2][2][64][36]; // partner-half swap (pad 36)

  const int tid  = threadIdx.x;
  const int g    = blockIdx.x;
  const int wave = tid >> 6, lane = tid & 63;
  const int wm   = wave >> 1, wn = wave & 1;
  const int l15  = lane & 15, l4 = lane >> 4;

  for (int i = tid; i < NV * 64; i += 256) {
    int v = i >> 6, c = i & 63;
    int j = (c >> 4) * NU + g * 16 + (c & 15);
    wx_lds[v][c] = Wx[v * N4U + j] + bias[j];
  }
  for (int i = tid; i < NB * 16; i += 256) {
    int r = i >> 4, u = i & 15;
    c_lds[r][u] = c0[r * NU + g * 16 + u];
  }
  for (int i = tid; i < NB * NT; i += 256) lab_lds[i] = (unsigned char)labels[i];

  // Wh B-fragments -> VGPRs, once (layout validated r1/r2/r4).
  bf16x8 bfrag[16][2];
#pragma unroll
  for (int kt = 0; kt < 16; ++kt) {
#pragma unroll
    for (int nt = 0; nt < 2; ++nt) {
      int c = wn * 32 + nt * 16 + l15;
      int j = (c >> 4) * NU + g * 16 + (c & 15);
      int kb = kt * 32 + l4 * 8;
      union { unsigned short us[8]; bf16x8 v; } bu;
#pragma unroll
      for (int e = 0; e < 8; ++e) bu.us[e] = f2bf(Wh[(kb + e) * N4U + j]);
      bfrag[kt][nt] = bu.v;
    }
  }

  // A-fragments from h0: lane holds h[arow][kt*32 + l4*8 + e], e=0..7.
  const int arow = wm * 16 + l15;
  u32x4 afrag[16];
#pragma unroll
  for (int kt = 0; kt < 16; ++kt) {
    const float* hp = h0 + arow * NU + kt * 32 + l4 * 8;
    u32x4 t;
    t.x = pk2(hp[0], hp[1]); t.y = pk2(hp[2], hp[3]);
    t.z = pk2(hp[4], hp[5]); t.w = pk2(hp[6], hp[7]);
    afrag[kt] = t;
  }

  const int bb = tid >> 3;          // batch handled in update phase
  const int u2 = (tid & 7) * 2;     // unit pair
  const int ci = g * 8 + (tid & 7); // pair index in [32][256] layout

  for (int s = 0; s < NT; ++s) {
    // [B] z = h @ WhSlice  (4 chains)
    f32x4 a00 = {0.f,0.f,0.f,0.f}, a01 = a00, a10 = a00, a11 = a00;
#pragma unroll
    for (int kt = 0; kt < 16; kt += 2) {
      bf16x8 av0 = __builtin_bit_cast(bf16x8, afrag[kt]);
      bf16x8 av1 = __builtin_bit_cast(bf16x8, afrag[kt + 1]);
      a00 = __builtin_amdgcn_mfma_f32_16x16x32_bf16(av0, bfrag[kt][0],     a00, 0, 0, 0);
      a10 = __builtin_amdgcn_mfma_f32_16x16x32_bf16(av0, bfrag[kt][1],     a10, 0, 0, 0);
      a01 = __builtin_amdgcn_mfma_f32_16x16x32_bf16(av1, bfrag[kt + 1][0], a01, 0, 0, 0);
      a11 = __builtin_amdgcn_mfma_f32_16x16x32_bf16(av1, bfrag[kt + 1][1], a11, 0, 0, 0);
    }
    f32x4 acc0 = a00 + a01, acc1 = a10 + a11;

    // [C] z -> LDS
#pragma unroll
    for (int ri = 0; ri < 4; ++ri) {
      z_buf[wm * 16 + l4 * 4 + ri][wn * 32 + l15]      = acc0[ri];
      z_buf[wm * 16 + l4 * 4 + ri][wn * 32 + 16 + l15] = acc1[ri];
    }
    __syncthreads();  // [D]

    // [E] gate update (thread owns (bb, u2..u2+1))
    int lab = lab_lds[bb * NT + s];
    float hv[2];
#pragma unroll
    for (int q = 0; q < 2; ++q) {
      int u = u2 + q;
      float zi = z_buf[bb][u]      + wx_lds[lab][u];
      float zf = z_buf[bb][16 + u] + wx_lds[lab][16 + u];
      float zg = z_buf[bb][32 + u] + wx_lds[lab][32 + u];
      float zo = z_buf[bb][48 + u] + wx_lds[lab][48 + u];
      float cc = sigf(zf) * c_lds[bb][u] + sigf(zi) * tanhfast(zg);
      c_lds[bb][u] = cc;
      hv[q] = sigf(zo) * tanhfast(cc);
    }
    u32 pkv = pk2(hv[0], hv[1]);
    dec_u[(bb * NT + s) * 256 + ci] = pkv;   // history (plain store)

    if (s == NT - 1) break;

    // [P] publish {data, tag} as ONE dwordx2 (same 8B transaction)
    {
      u32x2 v2; v2.x = pkv; v2.y = (u32)(s + 1);
      u32* sp = hbuf2 + (((s + 1) & 1) << 14) + bb * 512 + ci * 2;
      asm volatile("global_store_dwordx2 %0, %1, off sc0 sc1"
                   :: "v"(sp), "v"(v2) : "memory");
    }

    // [Q] poll own kt-half: 16 tagged dwordx4; tag==s+1 => data valid.
    u32x4 t[16];
    {
      const u32* qp = hbuf2 + (((s + 1) & 1) << 14) + arow * 512
                      + wn * 256 + l4 * 8;
      const u32 tg = (u32)(s + 1);
      int guard = 0;
      for (;;) {
        asm volatile(
          "global_load_dwordx4 %0, %16, off sc0 sc1\n\t"
          "global_load_dwordx4 %1, %16, off offset:16 sc0 sc1\n\t"
          "global_load_dwordx4 %2, %16, off offset:128 sc0 sc1\n\t"
          "global_load_dwordx4 %3, %16, off offset:144 sc0 sc1\n\t"
          "global_load_dwordx4 %4, %16, off offset:256 sc0 sc1\n\t"
          "global_load_dwordx4 %5, %16, off offset:272 sc0 sc1\n\t"
          "global_load_dwordx4 %6, %16, off offset:384 sc0 sc1\n\t"
          "global_load_dwordx4 %7, %16, off offset:400 sc0 sc1\n\t"
          "global_load_dwordx4 %8, %16, off offset:512 sc0 sc1\n\t"
          "global_load_dwordx4 %9, %16, off offset:528 sc0 sc1\n\t"
          "global_load_dwordx4 %10, %16, off offset:640 sc0 sc1\n\t"
          "global_load_dwordx4 %11, %16, off offset:656 sc0 sc1\n\t"
          "global_load_dwordx4 %12, %16, off offset:768 sc0 sc1\n\t"
          "global_load_dwordx4 %13, %16, off offset:784 sc0 sc1\n\t"
          "global_load_dwordx4 %14, %16, off offset:896 sc0 sc1\n\t"
          "global_load_dwordx4 %15, %16, off offset:912 sc0 sc1\n\t"
          "s_waitcnt vmcnt(0)"
          : "=&v"(t[0]),  "=&v"(t[1]),  "=&v"(t[2]),  "=&v"(t[3]),
            "=&v"(t[4]),  "=&v"(t[5]),  "=&v"(t[6]),  "=&v"(t[7]),
            "=&v"(t[8]),  "=&v"(t[9]),  "=&v"(t[10]), "=&v"(t[11]),
            "=&v"(t[12]), "=&v"(t[13]), "=&v"(t[14]), "=&v"(t[15])
          : "v"(qp)
          : "memory");
        bool ok = true;
#pragma unroll
        for (int i = 0; i < 16; ++i)
          ok = ok && (t[i].y == tg) && (t[i].w == tg);
        if (__all(ok)) break;
        if (++guard > 100000) break;  // anti-hang; break => visible absmax fail
        __builtin_amdgcn_s_sleep(1);
      }
    }

    // [X] own half -> afrag + LDS; partner half <- LDS. Static indices per
    // wn branch (rule #20: no runtime-indexed register arrays).
    {
      u32* hw = &hx[wm][wn][lane][0];
#pragma unroll
      for (int j = 0; j < 8; ++j) {
        u32x4 d; d.x = t[2*j].x; d.y = t[2*j].z; d.z = t[2*j+1].x; d.w = t[2*j+1].z;
        *reinterpret_cast<u32x4*>(hw + j * 4) = d;
        if (wn == 0) afrag[j] = d; else afrag[8 + j] = d;
      }
      __syncthreads();
      const u32* hr = &hx[wm][wn ^ 1][lane][0];
#pragma unroll
      for (int j = 0; j < 8; ++j) {
        u32x4 d = *reinterpret_cast<const u32x4*>(hr + j * 4);
        if (wn == 0) afrag[8 + j] = d; else afrag[j] = d;
      }
    }
    // loop: [C]'s syncthreads separates hx read (here) from next write
  }
}

// ---------------------------------------------------------------------------
// proj: rows 0..2047 -> d1 = dec@W1+b1 ; rows 2048..4095 -> e2 = enc@W2+b2.
// ---------------------------------------------------------------------------
__global__ __launch_bounds__(256, 1)
void proj_kernel(const u32* __restrict__ dec_u,
                 const float* __restrict__ enc,
                 const float* __restrict__ W1,
                 const float* __restrict__ b1,
                 const float* __restrict__ W2,
                 const float* __restrict__ b2,
                 unsigned short* __restrict__ d1_bf,
                 unsigned short* __restrict__ e2_bf)
{
  const int tid = threadIdx.x;
  const int wave = tid >> 6, lane = tid & 63;
  const int l15 = lane & 15, l4 = lane >> 4;
  const int w  = blockIdx.x * 4 + wave;   // 0..2047
  const int rt = w >> 3, cg = w & 7;
  const bool isdec = (rt < 128);
  const int r0 = (isdec ? rt : rt - 128) * 16;
  const float* Wm  = isdec ? W1 : W2;
  const float* bv_ = isdec ? b1 : b2;
  unsigned short* outp = isdec ? d1_bf : e2_bf;

  f32x4 acc[4] = {};
  const int arow = r0 + l15;
  for (int kt = 0; kt < 16; ++kt) {
    int k0 = kt * 32 + l4 * 8;
    bf16x8 a;
    if (isdec) {
      a = __builtin_bit_cast(bf16x8,
            *reinterpret_cast<const uint4*>(dec_u + arow * 256 + (k0 >> 1)));
    } else {
      const float* ep = enc + arow * NU + k0;
      union { unsigned short us[8]; bf16x8 v; } au;
#pragma unroll
      for (int e = 0; e < 8; ++e) au.us[e] = f2bf(ep[e]);
      a = au.v;
    }
#pragma unroll
    for (int nt = 0; nt < 4; ++nt) {
      int col = cg * 64 + nt * 16 + l15;
      union { unsigned short us[8]; bf16x8 v; } bu;
#pragma unroll
      for (int e = 0; e < 8; ++e) bu.us[e] = f2bf(Wm[(k0 + e) * NU + col]);
      acc[nt] = __builtin_amdgcn_mfma_f32_16x16x32_bf16(a, bu.v, acc[nt], 0, 0, 0);
    }
  }
#pragma unroll
  for (int nt = 0; nt < 4; ++nt) {
    int col = cg * 64 + nt * 16 + l15;
    float bc = bv_[col];
#pragma unroll
    for (int ri = 0; ri < 4; ++ri) {
      int row = r0 + l4 * 4 + ri;
      outp[row * NU + col] = f2bf(acc[nt][ri] + bc);
    }
  }
}

// ---------------------------------------------------------------------------
// score+softmax: one wave per (b,t); softmax over lanes; store out[b][s][t].
// ---------------------------------------------------------------------------
__global__ __launch_bounds__(256, 1)
void score_kernel(const unsigned short* __restrict__ d1_bf,
                  const unsigned short* __restrict__ e2_bf,
                  const float* __restrict__ V,
                  float* __restrict__ out)
{
  const int tid = threadIdx.x;
  const int wave = tid >> 6, lane = tid & 63;
  const int p = blockIdx.x * 4 + wave;   // 0..2047
  const int bb = p >> 6, t = p & 63;

  union { uint4 q; unsigned short us[8]; } dv;
  dv.q = *reinterpret_cast<const uint4*>(d1_bf + (bb * 64 + t) * NU + lane * 8);
  float d1f[8], Vf[8];
#pragma unroll
  for (int e = 0; e < 8; ++e) { d1f[e] = bf2f(dv.us[e]); Vf[e] = V[lane * 8 + e]; }

  float sc = 0.f;
  for (int s = 0; s < NS; ++s) {
    union { uint4 q; unsigned short us[8]; } ev;
    ev.q = *reinterpret_cast<const uint4*>(e2_bf + (bb * 64 + s) * NU + lane * 8);
    float part = 0.f;
#pragma unroll
    for (int e = 0; e < 8; ++e) part += tanhfast(d1f[e] + bf2f(ev.us[e])) * Vf[e];
#pragma unroll
    for (int o = 32; o > 0; o >>= 1) part += __shfl_xor(part, o);
    sc = (lane == s) ? part : sc;
  }
  float m = sc;
#pragma unroll
  for (int o = 32; o > 0; o >>= 1) m = fmaxf(m, __shfl_xor(m, o));
  float ex = __expf(sc - m);
  float sum = ex;
#pragma unroll
  for (int o = 32; o > 0; o >>= 1) sum += __shfl_xor(sum, o);
  out[(bb * 64 + lane) * 64 + t] = ex / sum;
}

// ---------------------------------------------------------------------------
extern "C" void kernel_launch(void* const* d_in, const int* in_sizes, int n_in,
                              void* d_out, int out_size, void* d_ws, size_t ws_size,
                              hipStream_t stream)
{
  (void)in_sizes; (void)n_in; (void)out_size;
  const int*   labels = (const int*)  d_in[0];
  const float* enc    = (const float*)d_in[1];
  const float* h0     = (const float*)d_in[2];
  const float* c0     = (const float*)d_in[3];
  const float* Wx     = (const float*)d_in[4];
  const float* Wh     = (const float*)d_in[5];
  const float* bias   = (const float*)d_in[6];
  const float* W1     = (const float*)d_in[7];
  const float* b1     = (const float*)d_in[8];
  const float* W2     = (const float*)d_in[9];
  const float* b2     = (const float*)d_in[10];
  const float* V      = (const float*)d_in[11];
  // d_in[12] = bv: additive scalar on all scores -> softmax-invariant.

  char* ws = (char*)d_ws;
  const size_t OFS_HB2 = 1024;                        // 128KB tagged exchange
  const size_t OFS_DEC = OFS_HB2 + (1u << 18);        // 2MB
  const size_t OFS_D1  = OFS_DEC + (2u << 20);        // 2MB
  const size_t OFS_E2  = OFS_D1  + (2u << 20);        // 2MB
  if (ws_size < OFS_E2 + (2u << 20)) return;

  u32* hbuf2 = (u32*)(ws + OFS_HB2);
  u32* dec_u = (u32*)(ws + OFS_DEC);
  unsigned short* d1_bf = (unsigned short*)(ws + OFS_D1);
  unsigned short* e2_bf = (unsigned short*)(ws + OFS_E2);
  float* out = (float*)d_out;

  lstm_kernel<<<dim3(NWG), dim3(256), 0, stream>>>(labels, h0, c0, Wx, Wh, bias,
                                                   hbuf2, dec_u);
  proj_kernel<<<dim3(512), dim3(256), 0, stream>>>(dec_u, enc, W1, b1, W2, b2,
                                                   d1_bf, e2_bf);
  score_kernel<<<dim3(512), dim3(256), 0, stream>>>(d1_bf, e2_bf, V, out);
}

// Round 6
// 428.515 us; speedup vs baseline: 1.0273x; 1.0273x over previous
//
#include <hip/hip_runtime.h>
#include <hip/hip_bf16.h>

// Decoder: one-hot@Wx gather -> 64-step LSTM -> Bahdanau attention softmax.
// B=32, T=64, S=64, U=512, 4U=2048, VOCAB=65.
//
// Round 6: hybrid exchange. r4 (flags+ack, clean single reload) = 4.93us/step;
// r5 (tagged data, poll-the-data) = 5.9us/step because every failed poll
// iteration re-read 16KB/wave. Now: tagged {data,epoch} 8B stores (keeps r5's
// deleted ack/flag RTs) + CHEAP 3x8B sample-poll hint + ONE validated full
// tagged load (retry only on straggler). LDS partner half-swap retained.
// e2 = enc@W2+b2 fused into the lstm dispatch as wgs 32..63 (runs on idle
// CUs in the recurrence's shadow); proj kernel is now d1-only.

#define NB 32
#define NT 64
#define NS 64
#define NU 512
#define N4U 2048
#define NV 65
#define NWG 32

typedef unsigned int u32;
typedef __bf16 bf16_t;
typedef bf16_t bf16x8 __attribute__((ext_vector_type(8)));
typedef float f32x4 __attribute__((ext_vector_type(4)));
typedef u32 u32x4 __attribute__((ext_vector_type(4)));
typedef u32 u32x2 __attribute__((ext_vector_type(2)));

__device__ __forceinline__ unsigned short f2bf(float f) {
  u32 u = __builtin_bit_cast(u32, f);
  u += 0x7fffu + ((u >> 16) & 1u);   // round-to-nearest-even
  return (unsigned short)(u >> 16);
}
__device__ __forceinline__ float bf2f(unsigned short s) {
  return __builtin_bit_cast(float, (u32)s << 16);
}
__device__ __forceinline__ u32 pk2(float a, float b) {
  return (u32)f2bf(a) | ((u32)f2bf(b) << 16);
}
__device__ __forceinline__ float sigf(float x) { return 1.0f / (1.0f + __expf(-x)); }
__device__ __forceinline__ float tanhfast(float x) {
  float e = __expf(2.0f * x);
  return 1.0f - 2.0f / (e + 1.0f);
}

// ---------------------------------------------------------------------------
// Fused kernel. wgs 0..31: LSTM recurrence (wg g owns h units [g*16,g*16+16)).
// wgs 32..63: e2 projection (wg owns 64 rows of enc@W2+b2).
// Exchange buffer hbuf2: [parity 2][row 32][pair 256][{data,tag} 2] u32.
// Tag monotonicity per location => correct across graph replays, no memset.
// ---------------------------------------------------------------------------
__global__ __launch_bounds__(256, 1)
void lstm_kernel(const int* __restrict__ labels,
                 const float* __restrict__ h0,
                 const float* __restrict__ c0,
                 const float* __restrict__ Wx,
                 const float* __restrict__ Wh,
                 const float* __restrict__ bias,
                 const float* __restrict__ enc,
                 const float* __restrict__ W2,
                 const float* __restrict__ b2,
                 u32* __restrict__ hbuf2,   // [2][32][256][2] tagged bf16-pairs
                 u32* __restrict__ dec_u,   // [32*64][256] bf16-pairs
                 unsigned short* __restrict__ e2_bf)
{
  __shared__ float z_buf[NB][65];            // padded: conflict-free gate reads
  __shared__ float c_lds[NB][16];
  __shared__ float wx_lds[NV][65];           // Wx slice + bias folded, padded
  __shared__ unsigned char lab_lds[NB * NT];
  __shared__ __align__(16) u32 hx[2][2][64][36]; // partner-half swap (pad 36)

  const int tid  = threadIdx.x;
  const int g    = blockIdx.x;
  const int wave = tid >> 6, lane = tid & 63;
  const int l15  = lane & 15, l4 = lane >> 4;

  // ------------------------- e2 wgs (32..63) -------------------------------
  if (g >= NWG) {
    const int r0 = (g - NWG) * 64 + wave * 16;   // 16 rows per wave
    const int arowE = r0 + l15;
    u32x4 afragE[16];
#pragma unroll
    for (int kt = 0; kt < 16; ++kt) {
      const float* ep = enc + arowE * NU + kt * 32 + l4 * 8;
      u32x4 t;
      t.x = pk2(ep[0], ep[1]); t.y = pk2(ep[2], ep[3]);
      t.z = pk2(ep[4], ep[5]); t.w = pk2(ep[6], ep[7]);
      afragE[kt] = t;
    }
    for (int cg = 0; cg < 8; ++cg) {
      f32x4 acc[4] = {};
      for (int kt = 0; kt < 16; ++kt) {
        bf16x8 a = __builtin_bit_cast(bf16x8, afragE[kt]);
        int k0 = kt * 32 + l4 * 8;
#pragma unroll
        for (int nt = 0; nt < 4; ++nt) {
          int col = cg * 64 + nt * 16 + l15;
          union { unsigned short us[8]; bf16x8 v; } bu;
#pragma unroll
          for (int e = 0; e < 8; ++e) bu.us[e] = f2bf(W2[(k0 + e) * NU + col]);
          acc[nt] = __builtin_amdgcn_mfma_f32_16x16x32_bf16(a, bu.v, acc[nt], 0, 0, 0);
        }
      }
#pragma unroll
      for (int nt = 0; nt < 4; ++nt) {
        int col = cg * 64 + nt * 16 + l15;
        float bc = b2[col];
#pragma unroll
        for (int ri = 0; ri < 4; ++ri)
          e2_bf[(r0 + l4 * 4 + ri) * NU + col] = f2bf(acc[nt][ri] + bc);
      }
    }
    return;
  }

  // ------------------------- LSTM wgs (0..31) ------------------------------
  const int wm = wave >> 1, wn = wave & 1;

  for (int i = tid; i < NV * 64; i += 256) {
    int v = i >> 6, c = i & 63;
    int j = (c >> 4) * NU + g * 16 + (c & 15);
    wx_lds[v][c] = Wx[v * N4U + j] + bias[j];
  }
  for (int i = tid; i < NB * 16; i += 256) {
    int r = i >> 4, u = i & 15;
    c_lds[r][u] = c0[r * NU + g * 16 + u];
  }
  for (int i = tid; i < NB * NT; i += 256) lab_lds[i] = (unsigned char)labels[i];

  // Wh B-fragments -> VGPRs, once (layout validated r1/r2/r4/r5).
  bf16x8 bfrag[16][2];
#pragma unroll
  for (int kt = 0; kt < 16; ++kt) {
#pragma unroll
    for (int nt = 0; nt < 2; ++nt) {
      int c = wn * 32 + nt * 16 + l15;
      int j = (c >> 4) * NU + g * 16 + (c & 15);
      int kb = kt * 32 + l4 * 8;
      union { unsigned short us[8]; bf16x8 v; } bu;
#pragma unroll
      for (int e = 0; e < 8; ++e) bu.us[e] = f2bf(Wh[(kb + e) * N4U + j]);
      bfrag[kt][nt] = bu.v;
    }
  }

  // A-fragments from h0: lane holds h[arow][kt*32 + l4*8 + e], e=0..7.
  const int arow = wm * 16 + l15;
  u32x4 afrag[16];
#pragma unroll
  for (int kt = 0; kt < 16; ++kt) {
    const float* hp = h0 + arow * NU + kt * 32 + l4 * 8;
    u32x4 t;
    t.x = pk2(hp[0], hp[1]); t.y = pk2(hp[2], hp[3]);
    t.z = pk2(hp[4], hp[5]); t.w = pk2(hp[6], hp[7]);
    afrag[kt] = t;
  }

  const int bb = tid >> 3;          // batch handled in update phase
  const int u2 = (tid & 7) * 2;     // unit pair
  const int ci = g * 8 + (tid & 7); // pair index in [32][256] layout

  for (int s = 0; s < NT; ++s) {
    // [B] z = h @ WhSlice  (4 chains)
    f32x4 a00 = {0.f,0.f,0.f,0.f}, a01 = a00, a10 = a00, a11 = a00;
#pragma unroll
    for (int kt = 0; kt < 16; kt += 2) {
      bf16x8 av0 = __builtin_bit_cast(bf16x8, afrag[kt]);
      bf16x8 av1 = __builtin_bit_cast(bf16x8, afrag[kt + 1]);
      a00 = __builtin_amdgcn_mfma_f32_16x16x32_bf16(av0, bfrag[kt][0],     a00, 0, 0, 0);
      a10 = __builtin_amdgcn_mfma_f32_16x16x32_bf16(av0, bfrag[kt][1],     a10, 0, 0, 0);
      a01 = __builtin_amdgcn_mfma_f32_16x16x32_bf16(av1, bfrag[kt + 1][0], a01, 0, 0, 0);
      a11 = __builtin_amdgcn_mfma_f32_16x16x32_bf16(av1, bfrag[kt + 1][1], a11, 0, 0, 0);
    }
    f32x4 acc0 = a00 + a01, acc1 = a10 + a11;

    // [C] z -> LDS
#pragma unroll
    for (int ri = 0; ri < 4; ++ri) {
      z_buf[wm * 16 + l4 * 4 + ri][wn * 32 + l15]      = acc0[ri];
      z_buf[wm * 16 + l4 * 4 + ri][wn * 32 + 16 + l15] = acc1[ri];
    }
    __syncthreads();  // [D]

    // [E] gate update (thread owns (bb, u2..u2+1))
    int lab = lab_lds[bb * NT + s];
    float hv[2];
#pragma unroll
    for (int q = 0; q < 2; ++q) {
      int u = u2 + q;
      float zi = z_buf[bb][u]      + wx_lds[lab][u];
      float zf = z_buf[bb][16 + u] + wx_lds[lab][16 + u];
      float zg = z_buf[bb][32 + u] + wx_lds[lab][32 + u];
      float zo = z_buf[bb][48 + u] + wx_lds[lab][48 + u];
      float cc = sigf(zf) * c_lds[bb][u] + sigf(zi) * tanhfast(zg);
      c_lds[bb][u] = cc;
      hv[q] = sigf(zo) * tanhfast(cc);
    }
    u32 pkv = pk2(hv[0], hv[1]);
    dec_u[(bb * NT + s) * 256 + ci] = pkv;   // history for d1 proj

    if (s == NT - 1) break;

    // [P] publish {data, tag} as ONE dwordx2 (tag implies its data)
    {
      u32x2 v2; v2.x = pkv; v2.y = (u32)(s + 1);
      u32* sp = hbuf2 + (((s + 1) & 1) << 14) + bb * 512 + ci * 2;
      asm volatile("global_store_dwordx2 %0, %1, off sc0 sc1"
                   :: "v"(sp), "v"(v2) : "memory");
    }

    const u32* qp = hbuf2 + (((s + 1) & 1) << 14) + arow * 512
                    + wn * 256 + l4 * 8;
    const u32 tg = (u32)(s + 1);

    // [Q1] cheap hint poll: 3 sampled tagged pairs (24B/lane/iter)
    {
      int guard = 0;
      for (;;) {
        u32x2 s0, s1, s2;
        asm volatile(
          "global_load_dwordx2 %0, %3, off sc0 sc1\n\t"
          "global_load_dwordx2 %1, %3, off offset:456 sc0 sc1\n\t"
          "global_load_dwordx2 %2, %3, off offset:920 sc0 sc1\n\t"
          "s_waitcnt vmcnt(0)"
          : "=&v"(s0), "=&v"(s1), "=&v"(s2)
          : "v"(qp) : "memory");
        if (__all(s0.y == tg && s1.y == tg && s2.y == tg)) break;
        if (++guard > 200000) break;  // anti-hang
        __builtin_amdgcn_s_sleep(1);
      }
    }

    // [Q2] one full tagged load of own kt-half + validate (retry if straggler)
    u32x4 t[16];
    {
      int guard = 0;
      for (;;) {
        asm volatile(
          "global_load_dwordx4 %0, %16, off sc0 sc1\n\t"
          "global_load_dwordx4 %1, %16, off offset:16 sc0 sc1\n\t"
          "global_load_dwordx4 %2, %16, off offset:128 sc0 sc1\n\t"
          "global_load_dwordx4 %3, %16, off offset:144 sc0 sc1\n\t"
          "global_load_dwordx4 %4, %16, off offset:256 sc0 sc1\n\t"
          "global_load_dwordx4 %5, %16, off offset:272 sc0 sc1\n\t"
          "global_load_dwordx4 %6, %16, off offset:384 sc0 sc1\n\t"
          "global_load_dwordx4 %7, %16, off offset:400 sc0 sc1\n\t"
          "global_load_dwordx4 %8, %16, off offset:512 sc0 sc1\n\t"
          "global_load_dwordx4 %9, %16, off offset:528 sc0 sc1\n\t"
          "global_load_dwordx4 %10, %16, off offset:640 sc0 sc1\n\t"
          "global_load_dwordx4 %11, %16, off offset:656 sc0 sc1\n\t"
          "global_load_dwordx4 %12, %16, off offset:768 sc0 sc1\n\t"
          "global_load_dwordx4 %13, %16, off offset:784 sc0 sc1\n\t"
          "global_load_dwordx4 %14, %16, off offset:896 sc0 sc1\n\t"
          "global_load_dwordx4 %15, %16, off offset:912 sc0 sc1\n\t"
          "s_waitcnt vmcnt(0)"
          : "=&v"(t[0]),  "=&v"(t[1]),  "=&v"(t[2]),  "=&v"(t[3]),
            "=&v"(t[4]),  "=&v"(t[5]),  "=&v"(t[6]),  "=&v"(t[7]),
            "=&v"(t[8]),  "=&v"(t[9]),  "=&v"(t[10]), "=&v"(t[11]),
            "=&v"(t[12]), "=&v"(t[13]), "=&v"(t[14]), "=&v"(t[15])
          : "v"(qp)
          : "memory");
        bool ok = true;
#pragma unroll
        for (int i = 0; i < 16; ++i)
          ok = ok && (t[i].y == tg) && (t[i].w == tg);
        if (__all(ok)) break;
        if (++guard > 20000) break;   // anti-hang
        __builtin_amdgcn_s_sleep(1);
      }
    }

    // [X] own half -> afrag + LDS; partner half <- LDS (static idx per wn).
    {
      u32* hw = &hx[wm][wn][lane][0];
#pragma unroll
      for (int j = 0; j < 8; ++j) {
        u32x4 d; d.x = t[2*j].x; d.y = t[2*j].z; d.z = t[2*j+1].x; d.w = t[2*j+1].z;
        *reinterpret_cast<u32x4*>(hw + j * 4) = d;
        if (wn == 0) afrag[j] = d; else afrag[8 + j] = d;
      }
      __syncthreads();
      const u32* hr = &hx[wm][wn ^ 1][lane][0];
#pragma unroll
      for (int j = 0; j < 8; ++j) {
        u32x4 d = *reinterpret_cast<const u32x4*>(hr + j * 4);
        if (wn == 0) afrag[8 + j] = d; else afrag[j] = d;
      }
    }
    // loop: [D]'s syncthreads separates hx read (here) from next write
  }
}

// ---------------------------------------------------------------------------
// proj (d1 only): d1 = dec@W1+b1. One wave = 16 rows x 64 cols. grid 256x256.
// ---------------------------------------------------------------------------
__global__ __launch_bounds__(256, 1)
void proj_kernel(const u32* __restrict__ dec_u,
                 const float* __restrict__ W1,
                 const float* __restrict__ b1,
                 unsigned short* __restrict__ d1_bf)
{
  const int tid = threadIdx.x;
  const int wave = tid >> 6, lane = tid & 63;
  const int l15 = lane & 15, l4 = lane >> 4;
  const int w  = blockIdx.x * 4 + wave;   // 0..1023
  const int rt = w >> 3, cg = w & 7;
  const int r0 = rt * 16;

  f32x4 acc[4] = {};
  const int arow = r0 + l15;
  for (int kt = 0; kt < 16; ++kt) {
    int k0 = kt * 32 + l4 * 8;
    bf16x8 a = __builtin_bit_cast(bf16x8,
          *reinterpret_cast<const uint4*>(dec_u + arow * 256 + (k0 >> 1)));
#pragma unroll
    for (int nt = 0; nt < 4; ++nt) {
      int col = cg * 64 + nt * 16 + l15;
      union { unsigned short us[8]; bf16x8 v; } bu;
#pragma unroll
      for (int e = 0; e < 8; ++e) bu.us[e] = f2bf(W1[(k0 + e) * NU + col]);
      acc[nt] = __builtin_amdgcn_mfma_f32_16x16x32_bf16(a, bu.v, acc[nt], 0, 0, 0);
    }
  }
#pragma unroll
  for (int nt = 0; nt < 4; ++nt) {
    int col = cg * 64 + nt * 16 + l15;
    float bc = b1[col];
#pragma unroll
    for (int ri = 0; ri < 4; ++ri) {
      int row = r0 + l4 * 4 + ri;
      d1_bf[row * NU + col] = f2bf(acc[nt][ri] + bc);
    }
  }
}

// ---------------------------------------------------------------------------
// score+softmax: one wave per (b,t); softmax over lanes; store out[b][s][t].
// ---------------------------------------------------------------------------
__global__ __launch_bounds__(256, 1)
void score_kernel(const unsigned short* __restrict__ d1_bf,
                  const unsigned short* __restrict__ e2_bf,
                  const float* __restrict__ V,
                  float* __restrict__ out)
{
  const int tid = threadIdx.x;
  const int wave = tid >> 6, lane = tid & 63;
  const int p = blockIdx.x * 4 + wave;   // 0..2047
  const int bb = p >> 6, t = p & 63;

  union { uint4 q; unsigned short us[8]; } dv;
  dv.q = *reinterpret_cast<const uint4*>(d1_bf + (bb * 64 + t) * NU + lane * 8);
  float d1f[8], Vf[8];
#pragma unroll
  for (int e = 0; e < 8; ++e) { d1f[e] = bf2f(dv.us[e]); Vf[e] = V[lane * 8 + e]; }

  float sc = 0.f;
  for (int s = 0; s < NS; ++s) {
    union { uint4 q; unsigned short us[8]; } ev;
    ev.q = *reinterpret_cast<const uint4*>(e2_bf + (bb * 64 + s) * NU + lane * 8);
    float part = 0.f;
#pragma unroll
    for (int e = 0; e < 8; ++e) part += tanhfast(d1f[e] + bf2f(ev.us[e])) * Vf[e];
#pragma unroll
    for (int o = 32; o > 0; o >>= 1) part += __shfl_xor(part, o);
    sc = (lane == s) ? part : sc;
  }
  float m = sc;
#pragma unroll
  for (int o = 32; o > 0; o >>= 1) m = fmaxf(m, __shfl_xor(m, o));
  float ex = __expf(sc - m);
  float sum = ex;
#pragma unroll
  for (int o = 32; o > 0; o >>= 1) sum += __shfl_xor(sum, o);
  out[(bb * 64 + lane) * 64 + t] = ex / sum;
}

// ---------------------------------------------------------------------------
extern "C" void kernel_launch(void* const* d_in, const int* in_sizes, int n_in,
                              void* d_out, int out_size, void* d_ws, size_t ws_size,
                              hipStream_t stream)
{
  (void)in_sizes; (void)n_in; (void)out_size;
  const int*   labels = (const int*)  d_in[0];
  const float* enc    = (const float*)d_in[1];
  const float* h0     = (const float*)d_in[2];
  const float* c0     = (const float*)d_in[3];
  const float* Wx     = (const float*)d_in[4];
  const float* Wh     = (const float*)d_in[5];
  const float* bias   = (const float*)d_in[6];
  const float* W1     = (const float*)d_in[7];
  const float* b1     = (const float*)d_in[8];
  const float* W2     = (const float*)d_in[9];
  const float* b2     = (const float*)d_in[10];
  const float* V      = (const float*)d_in[11];
  // d_in[12] = bv: additive scalar on all scores -> softmax-invariant.

  char* ws = (char*)d_ws;
  const size_t OFS_HB2 = 1024;                        // 128KB tagged exchange
  const size_t OFS_DEC = OFS_HB2 + (1u << 18);        // 2MB
  const size_t OFS_D1  = OFS_DEC + (2u << 20);        // 2MB
  const size_t OFS_E2  = OFS_D1  + (2u << 20);        // 2MB
  if (ws_size < OFS_E2 + (2u << 20)) return;

  u32* hbuf2 = (u32*)(ws + OFS_HB2);
  u32* dec_u = (u32*)(ws + OFS_DEC);
  unsigned short* d1_bf = (unsigned short*)(ws + OFS_D1);
  unsigned short* e2_bf = (unsigned short*)(ws + OFS_E2);
  float* out = (float*)d_out;

  lstm_kernel<<<dim3(2 * NWG), dim3(256), 0, stream>>>(labels, h0, c0, Wx, Wh,
                                                       bias, enc, W2, b2,
                                                       hbuf2, dec_u, e2_bf);
  proj_kernel<<<dim3(256), dim3(256), 0, stream>>>(dec_u, W1, b1, d1_bf);
  score_kernel<<<dim3(512), dim3(256), 0, stream>>>(d1_bf, e2_bf, V, out);
}